// Round 1
// baseline (479.670 us; speedup 1.0000x reference)
//
#include <hip/hip_runtime.h>
#include <stdint.h>

// ============================================================================
// Attention_68066641707351 : b=4, c=512, n=64*64=4096
//   f = x^T (per batch)        [n, c]
//   Q = f w1^T                 [n, d]
//   S = Q f^T / sqrt(512)      [n, m]
//   P = softmax_rows(S)
//   V = f w2^T                 [m, d]
//   out[b,d,n] = (P V)^T
// Pipeline: cast W -> transpose x -> GEMM Q -> GEMM Vt -> fused flash attn.
// All matmuls bf16 MFMA, f32 accumulate.
// ============================================================================

typedef __attribute__((ext_vector_type(8)))  short          short8;
typedef __attribute__((ext_vector_type(4)))  float          f32x4;
typedef __attribute__((ext_vector_type(16))) float          f32x16;
typedef __attribute__((ext_vector_type(4)))  unsigned short u16x4;
typedef __attribute__((ext_vector_type(8)))  unsigned short u16x8;

#define N_TOK 4096
#define CDIM  512

static __device__ __forceinline__ unsigned short f2bf(float f){
  unsigned int u = __builtin_bit_cast(unsigned int, f);
  u += 0x7fffu + ((u >> 16) & 1u);            // round-to-nearest-even
  return (unsigned short)(u >> 16);
}
static __device__ __forceinline__ unsigned int pk2bf(float a, float b){
  unsigned int ua = __builtin_bit_cast(unsigned int, a);
  ua += 0x7fffu + ((ua >> 16) & 1u);
  unsigned int ub = __builtin_bit_cast(unsigned int, b);
  ub += 0x7fffu + ((ub >> 16) & 1u);
  return (ua >> 16) | (ub & 0xffff0000u);
}
// async global->LDS, 16B per lane; l must be wave-uniform base (HW adds lane*16)
static __device__ __forceinline__ void gl_lds16(const void* g, void* l){
  __builtin_amdgcn_global_load_lds((__attribute__((address_space(1))) void*)g,
                                   (__attribute__((address_space(3))) void*)l,
                                   16, 0, 0);
}

// ---------------------------------------------------------------------------
// kernel 0: cast w1,w2 (512x512 f32) -> bf16
// ---------------------------------------------------------------------------
__global__ void k_castw(const float* __restrict__ w1, const float* __restrict__ w2,
                        unsigned short* __restrict__ w1b, unsigned short* __restrict__ w2b){
  int i = blockIdx.x * 256 + threadIdx.x;          // 65536 threads, 4 f32 each
  float4 a = ((const float4*)w1)[i];
  float4 c = ((const float4*)w2)[i];
  u16x4 oa = { f2bf(a.x), f2bf(a.y), f2bf(a.z), f2bf(a.w) };
  u16x4 oc = { f2bf(c.x), f2bf(c.y), f2bf(c.z), f2bf(c.w) };
  *(u16x4*)(w1b + (size_t)i*4) = oa;
  *(u16x4*)(w2b + (size_t)i*4) = oc;
}

// ---------------------------------------------------------------------------
// kernel 1: Kb[b][n][c] = bf16( x[b][c][n] )   (64x64 LDS tile transpose)
// grid (64 n-tiles, 8 c-tiles, 4 b), block 256
// ---------------------------------------------------------------------------
__global__ void k_transpose(const float* __restrict__ x, unsigned short* __restrict__ Kb){
  __shared__ float tile[64][65];
  const int b = blockIdx.z, c0 = blockIdx.y*64, n0 = blockIdx.x*64;
  const int t = threadIdx.x;
#pragma unroll
  for(int i=0;i<4;i++){
    int flat = i*256 + t;                 // 64 rows x 16 float4
    int row = flat>>4, ch = flat&15;
    float4 v = *(const float4*)(x + ((size_t)(b*CDIM + c0 + row))*N_TOK + n0 + ch*4);
    tile[row][ch*4+0]=v.x; tile[row][ch*4+1]=v.y; tile[row][ch*4+2]=v.z; tile[row][ch*4+3]=v.w;
  }
  __syncthreads();
#pragma unroll
  for(int i=0;i<2;i++){
    int flat = i*256 + t;                 // 64 n-rows x 8 chunks(8 bf16)
    int nr = flat>>3, cc = flat&7;
    u16x8 o;
#pragma unroll
    for(int e=0;e<8;e++) o[e] = f2bf(tile[cc*8+e][nr]);
    *(u16x8*)(Kb + ((size_t)b*N_TOK + n0 + nr)*CDIM + c0 + cc*8) = o;
  }
}

// ---------------------------------------------------------------------------
// kernel 2: BT-GEMM  C[m][n] = sum_k Arow[m][k] * Brow[n][k]   (K = 512, bf16)
// 128x128 block tile, 4 waves (2x2) of 64x64, 16x16x32 MFMA, BK=32,
// linear LDS staged via global_load_lds (conflict-free for this frag pattern).
// ---------------------------------------------------------------------------
__global__ __launch_bounds__(256, 2)
void k_gemm_bt(const unsigned short* __restrict__ A, const unsigned short* __restrict__ B,
               unsigned short* __restrict__ C,
               long Abstride, long Bbstride, long Cbstride, int ldc)
{
  __shared__ unsigned short Asm[128*32];
  __shared__ unsigned short Bsm[128*32];
  const int b = blockIdx.z;
  const unsigned short* Ab = A + (size_t)b*Abstride;
  const unsigned short* Bb = B + (size_t)b*Bbstride;
  unsigned short* Cb = C + (size_t)b*Cbstride;
  const int t = threadIdx.x, w = t>>6, lane = t&63;
  const int wr = w>>1, wc = w&1;
  const size_t am0 = (size_t)blockIdx.x*128;
  const size_t bn0 = (size_t)blockIdx.y*128;

  f32x4 acc[4][4];
#pragma unroll
  for(int i=0;i<4;i++)
#pragma unroll
    for(int j=0;j<4;j++)
#pragma unroll
      for(int r=0;r<4;r++) acc[i][j][r]=0.f;

  for(int k0=0;k0<CDIM;k0+=32){
#pragma unroll
    for(int i=0;i<2;i++){
      int flat = i*256 + t;               // 128 rows x 4 chunks(16B)
      int row = flat>>2, ch = flat&3;
      gl_lds16(Ab + (am0+row)*CDIM + k0 + ch*8, &Asm[(size_t)(i*256 + w*64)*8]);
    }
#pragma unroll
    for(int i=0;i<2;i++){
      int flat = i*256 + t;
      int row = flat>>2, ch = flat&3;
      gl_lds16(Bb + (bn0+row)*CDIM + k0 + ch*8, &Bsm[(size_t)(i*256 + w*64)*8]);
    }
    __syncthreads();
    short8 af[4], bfr[4];
#pragma unroll
    for(int i=0;i<4;i++){
      af[i]  = *(const short8*)&Asm[(wr*64 + i*16 + (lane&15))*32 + (lane>>4)*8];
      bfr[i] = *(const short8*)&Bsm[(wc*64 + i*16 + (lane&15))*32 + (lane>>4)*8];
    }
#pragma unroll
    for(int i=0;i<4;i++)
#pragma unroll
      for(int j=0;j<4;j++)
        acc[i][j] = __builtin_amdgcn_mfma_f32_16x16x32_bf16(af[i], bfr[j], acc[i][j], 0,0,0);
    __syncthreads();
  }
  // epilogue: C/D map col=lane&15, row=(lane>>4)*4+r ; write bf16
#pragma unroll
  for(int i=0;i<4;i++)
#pragma unroll
    for(int j=0;j<4;j++){
      size_t m0 = am0 + wr*64 + i*16 + (lane>>4)*4;
      size_t n  = bn0 + wc*64 + j*16 + (lane&15);
#pragma unroll
      for(int r=0;r<4;r++)
        Cb[(m0+r)*(size_t)ldc + n] = f2bf(acc[i][j][r]);
    }
}

// ---------------------------------------------------------------------------
// kernel 3: fused flash attention.
// grid (64 n-blocks, 4 b), block 256 = 4 waves: wave = (rg, h)
//   rg: 32 q-rows (q0 = nb*64 + rg*32), h: d-half [h*256, h*256+256)
// Swapped operands: S^T = mfma(Kfrag, Qfrag); O^T = mfma(Vfrag, Pfrag).
// Lane roles: ql = lane&31 = q-column (softmax lane-local), hp = lane>>5.
// LDS: Ks[64][512], Vs[512][64] bf16, chunk16-swizzled with (row&7) XOR
// (source pre-swizzled for global_load_lds; reads XOR back) -> conflict-free.
// ---------------------------------------------------------------------------
__global__ __launch_bounds__(256, 1)
void k_attn(const unsigned short* __restrict__ Qb, const unsigned short* __restrict__ Kb,
            const unsigned short* __restrict__ Vt, float* __restrict__ out)
{
  __shared__ unsigned short Ks[64*512];   // 64 KB
  __shared__ unsigned short Vs[512*64];   // 64 KB
  const int b = blockIdx.y, nb = blockIdx.x;
  const int t = threadIdx.x, w = t>>6, lane = t&63;
  const int rg = w>>1, h = w&1;
  const int hp = lane>>5, ql = lane&31;
  const int q0 = nb*64 + rg*32;
  const size_t bK = (size_t)b*N_TOK*CDIM;

  // Q fragments, full c=512: qreg[s] holds Q[q0+ql][s*16 + hp*8 + e]
  short8 qreg[32];
  {
    const unsigned short* qrow = Qb + bK + (size_t)(q0+ql)*CDIM + hp*8;
#pragma unroll
    for(int s=0;s<32;s++) qreg[s] = *(const short8*)(qrow + s*16);
  }

  f32x16 accO[8];                          // O^T: 8 d-tiles of 32 x (32 q)
#pragma unroll
  for(int j=0;j<8;j++)
#pragma unroll
    for(int p=0;p<16;p++) accO[j][p]=0.f;

  float mrun = -1e30f, lsum = 0.f;
  const float LAM = 0.04419417382415922f * 1.44269504088896340f; // 1/sqrt(512)*log2(e)

  for(int kt=0; kt<64; ++kt){
    const int kv0 = kt*64;
    // ---- stage K tile: wave-issue j stages row r = j*4+w (1 KB), swizzled src
#pragma unroll
    for(int j=0;j<16;j++){
      int r = j*4 + w;
      gl_lds16(Kb + bK + (size_t)(kv0+r)*CDIM + ((lane ^ (r&7))*8), &Ks[(size_t)r*512]);
    }
    // ---- stage V tile: Vt rows (d-major), 128B per row, swizzled src
#pragma unroll
    for(int j=0;j<16;j++){
      int base = (j*4+w)*64;
      int flat = base + lane;
      int r = flat>>3, wc = flat&7;
      gl_lds16(Vt + (size_t)b*CDIM*N_TOK + (size_t)r*N_TOK + kv0 + ((wc ^ (r&7))*8),
               &Vs[(size_t)base*8]);
    }
    __syncthreads();

    // ---- S^T = K * Q^T over full c (both waves of an rg compute identically)
    f32x16 s0, s1;
#pragma unroll
    for(int p=0;p<16;p++){ s0[p]=0.f; s1[p]=0.f; }
#pragma unroll
    for(int s=0;s<32;s++){
      int ch = 2*s + hp;
      short8 kf0 = *(const short8*)&Ks[(size_t)ql*512      + ((ch ^ (ql&7))*8)];
      short8 kf1 = *(const short8*)&Ks[(size_t)(32+ql)*512 + ((ch ^ (ql&7))*8)];
      s0 = __builtin_amdgcn_mfma_f32_32x32x16_bf16(kf0, qreg[s], s0, 0,0,0);
      s1 = __builtin_amdgcn_mfma_f32_32x32x16_bf16(kf1, qreg[s], s1, 0,0,0);
    }

    // ---- online softmax in z = S*LAM (log2) domain; lane pair (l, l^32) spans kv
    float zmax = -1e30f;
#pragma unroll
    for(int p=0;p<16;p++){
      s0[p]*=LAM; s1[p]*=LAM;
      zmax = fmaxf(zmax, fmaxf(s0[p], s1[p]));
    }
    zmax = fmaxf(zmax, __shfl_xor(zmax, 32));
    float mnew  = fmaxf(mrun, zmax);
    float alpha = exp2f(mrun - mnew);
    mrun = mnew;
    float ps = 0.f;
#pragma unroll
    for(int p=0;p<16;p++){
      float e0 = exp2f(s0[p]-mnew), e1 = exp2f(s1[p]-mnew);
      s0[p]=e0; s1[p]=e1; ps += e0+e1;
    }
    ps += __shfl_xor(ps, 32);
    lsum = lsum*alpha + ps;
#pragma unroll
    for(int j=0;j<8;j++)
#pragma unroll
      for(int p=0;p<16;p++) accO[j][p] *= alpha;

    // ---- P -> bf16 B-fragments (pk + shfl_xor32 redistribution), then PV
#pragma unroll
    for(int s=0;s<4;s++){                  // kv-step of 16 within the 64-tile
      f32x16& SS = (s>>1) ? s1 : s0;
      const int s2 = s&1;
      unsigned wA0 = pk2bf(SS[s2*8+0], SS[s2*8+1]);
      unsigned wA1 = pk2bf(SS[s2*8+2], SS[s2*8+3]);
      unsigned wB0 = pk2bf(SS[s2*8+4], SS[s2*8+5]);
      unsigned wB1 = pk2bf(SS[s2*8+6], SS[s2*8+7]);
      unsigned o0 = __shfl_xor(wB0, 32);
      unsigned o1 = __shfl_xor(wB1, 32);
      unsigned o2 = __shfl_xor(wA0, 32);
      unsigned o3 = __shfl_xor(wA1, 32);
      union { unsigned u[4]; short8 v; } pu;
      pu.u[0] = hp ? o0 : wA0;
      pu.u[1] = hp ? o1 : wA1;
      pu.u[2] = hp ? wB0 : o2;
      pu.u[3] = hp ? wB1 : o3;
      short8 pf = pu.v;                    // P^T[kv = s*16+hp*8+e][q=ql]
#pragma unroll
      for(int j=0;j<8;j++){
        int vrow = h*256 + j*32 + ql;
        int ch = (2*s + hp) ^ (vrow&7);
        short8 vf = *(const short8*)&Vs[(size_t)vrow*64 + ch*8];
        accO[j] = __builtin_amdgcn_mfma_f32_32x32x16_bf16(vf, pf, accO[j], 0,0,0);
      }
    }
    __syncthreads();                       // protect Ks/Vs before next stage
  }

  // ---- epilogue: out[b][d][q] = O^T / lsum  (C/D: col=ql=q, row->d)
  const float inv = 1.0f / lsum;
#pragma unroll
  for(int j=0;j<8;j++)
#pragma unroll
    for(int p=0;p<16;p++){
      int d = h*256 + j*32 + (p&3) + 8*(p>>2) + 4*hp;
      out[(size_t)b*CDIM*N_TOK + (size_t)d*N_TOK + q0 + ql] = accO[j][p]*inv;
    }
}

// ---------------------------------------------------------------------------
extern "C" void kernel_launch(void* const* d_in, const int* in_sizes, int n_in,
                              void* d_out, int out_size, void* d_ws, size_t ws_size,
                              hipStream_t stream)
{
  const float* x  = (const float*)d_in[0];
  const float* w1 = (const float*)d_in[1];
  const float* w2 = (const float*)d_in[2];
  float* out = (float*)d_out;

  // workspace layout (ushort units): w1b | w2b | Kb | Qb | Vtb  (~49 MiB total)
  unsigned short* ws  = (unsigned short*)d_ws;
  unsigned short* w1b = ws;
  unsigned short* w2b = ws + 262144;
  unsigned short* Kb  = ws + 524288;
  unsigned short* Qb  = Kb + (size_t)4*N_TOK*CDIM;
  unsigned short* Vtb = Qb + (size_t)4*N_TOK*CDIM;

  k_castw    <<<256, 256, 0, stream>>>(w1, w2, w1b, w2b);
  k_transpose<<<dim3(64,8,4), 256, 0, stream>>>(x, Kb);
  // Q[n][d] = sum_c Kb[n][c] * w1b[d][c]      (A batch-strided, B shared)
  k_gemm_bt  <<<dim3(32,4,4), 256, 0, stream>>>(Kb, w1b, Qb,
              (long)N_TOK*CDIM, 0L, (long)N_TOK*CDIM, CDIM);
  // Vt[d][n] = sum_c w2b[d][c] * Kb[n][c]     (A shared, B batch-strided)
  k_gemm_bt  <<<dim3(4,32,4), 256, 0, stream>>>(w2b, Kb, Vtb,
              0L, (long)N_TOK*CDIM, (long)CDIM*N_TOK, N_TOK);
  k_attn     <<<dim3(64,4), 256, 0, stream>>>(Qb, Kb, Vtb, out);
}